// Round 1
// baseline (15467.346 us; speedup 1.0000x reference)
//
#include <hip/hip_runtime.h>
#include <hip/hip_bf16.h>
#include <hip/hip_cooperative_groups.h>

namespace cg = cooperative_groups;

#define TT 128   // time steps
#define BB 1024  // batch
#define DD 256   // deter dim
#define SS 32    // stoch dim
#define HHID 256 // hidden
#define NC 1280  // combined phase-A output cols: 256 P1 | 256 Q1 | 768 gh

__device__ __forceinline__ float eluf(float x) { return x > 0.f ? x : expm1f(x); }
__device__ __forceinline__ float sigf(float x) { return 1.f / (1.f + expf(-x)); }
__device__ __forceinline__ float clip75(float x) { return fminf(fmaxf(x, -7.f), 5.f); }

// ---------------- weight transpose: dst[k*dld + dcoff + n] = src[n*sld + soff + k] ----------------
__global__ void transpose_k(const float* __restrict__ src, float* __restrict__ dst,
                            int N, int K, int soff, int sld, int dld, int dcoff)
{
    int idx = blockIdx.x * 256 + threadIdx.x;
    if (idx >= N * K) return;
    int k = idx / N, n = idx - k * N;
    dst[k * dld + dcoff + n] = src[n * sld + soff + k];
}

// ---------------- fused obs encoder -> Qpre[t][b][:] = emb @ Wq1_e^T + b_q1 ----------------
// 32 rows per block, 256 threads: tx=tid&31 -> cols tx*8..+7, ty=tid>>5 -> rows ty*4..+3
template <typename QT>
__global__ void __launch_bounds__(256) obs_enc_k(
    const float* __restrict__ obs, const float* __restrict__ We1t,
    const float* __restrict__ be1, const float* __restrict__ We2t,
    const float* __restrict__ be2, const float* __restrict__ Wq1et,
    const float* __restrict__ bq1, QT* __restrict__ Qpre)
{
    __shared__ float buf0[32 * 256];
    __shared__ float buf1[32 * 256];
    const int tid = threadIdx.x;
    const int r0 = blockIdx.x * 32;
    const int tx = tid & 31, ty = tid >> 5;
    const int colb = tx * 8;
    float acc[4][8];

    // ---- layer 1: E1 = elu(obs @ We1^T + be1), K = 64 ----
#pragma unroll
    for (int i = 0; i < 4; ++i)
#pragma unroll
        for (int j = 0; j < 8; ++j) acc[i][j] = 0.f;
#pragma unroll 4
    for (int k = 0; k < 64; ++k) {
        float4 w0 = *(const float4*)&We1t[k * 256 + colb];
        float4 w1 = *(const float4*)&We1t[k * 256 + colb + 4];
#pragma unroll
        for (int i = 0; i < 4; ++i) {
            float a = obs[(r0 + ty * 4 + i) * 64 + k];
            acc[i][0] += a * w0.x; acc[i][1] += a * w0.y; acc[i][2] += a * w0.z; acc[i][3] += a * w0.w;
            acc[i][4] += a * w1.x; acc[i][5] += a * w1.y; acc[i][6] += a * w1.z; acc[i][7] += a * w1.w;
        }
    }
#pragma unroll
    for (int i = 0; i < 4; ++i)
#pragma unroll
        for (int j = 0; j < 8; ++j)
            buf0[(ty * 4 + i) * 256 + colb + j] = eluf(acc[i][j] + be1[colb + j]);
    __syncthreads();

    // ---- layer 2: emb = elu(E1 @ We2^T + be2), K = 256 ----
#pragma unroll
    for (int i = 0; i < 4; ++i)
#pragma unroll
        for (int j = 0; j < 8; ++j) acc[i][j] = 0.f;
#pragma unroll 4
    for (int k = 0; k < 256; ++k) {
        float4 w0 = *(const float4*)&We2t[k * 256 + colb];
        float4 w1 = *(const float4*)&We2t[k * 256 + colb + 4];
#pragma unroll
        for (int i = 0; i < 4; ++i) {
            float a = buf0[(ty * 4 + i) * 256 + k];
            acc[i][0] += a * w0.x; acc[i][1] += a * w0.y; acc[i][2] += a * w0.z; acc[i][3] += a * w0.w;
            acc[i][4] += a * w1.x; acc[i][5] += a * w1.y; acc[i][6] += a * w1.z; acc[i][7] += a * w1.w;
        }
    }
#pragma unroll
    for (int i = 0; i < 4; ++i)
#pragma unroll
        for (int j = 0; j < 8; ++j)
            buf1[(ty * 4 + i) * 256 + colb + j] = eluf(acc[i][j] + be2[colb + j]);
    __syncthreads();

    // ---- layer 3: Qpre = emb @ Wq1_e^T + b_q1 (no activation), K = 256 ----
#pragma unroll
    for (int i = 0; i < 4; ++i)
#pragma unroll
        for (int j = 0; j < 8; ++j) acc[i][j] = 0.f;
#pragma unroll 4
    for (int k = 0; k < 256; ++k) {
        float4 w0 = *(const float4*)&Wq1et[k * 256 + colb];
        float4 w1 = *(const float4*)&Wq1et[k * 256 + colb + 4];
#pragma unroll
        for (int i = 0; i < 4; ++i) {
            float a = buf1[(ty * 4 + i) * 256 + k];
            acc[i][0] += a * w0.x; acc[i][1] += a * w0.y; acc[i][2] += a * w0.z; acc[i][3] += a * w0.w;
            acc[i][4] += a * w1.x; acc[i][5] += a * w1.y; acc[i][6] += a * w1.z; acc[i][7] += a * w1.w;
        }
    }
#pragma unroll
    for (int i = 0; i < 4; ++i) {
        int r = r0 + ty * 4 + i;
        int b = r >> 7;         // row = b*T + t
        int t = r & (TT - 1);
        QT* dst = Qpre + ((size_t)t * BB + b) * HHID + colb;
#pragma unroll
        for (int j = 0; j < 8; ++j)
            dst[j] = (QT)(acc[i][j] + bq1[colb + j]);
    }
}

// ---------------- cooperative sequential scan ----------------
template <typename QT>
__global__ void __launch_bounds__(256) seq_k(
    const float* __restrict__ act, const float* __restrict__ noise,
    const float* __restrict__ Wcombt, const float* __restrict__ b_p1,
    const float* __restrict__ b_hh, const QT* __restrict__ Qpre,
    const float* __restrict__ Wp2t, const float* __restrict__ b_p2,
    const float* __restrict__ Wq2t, const float* __restrict__ b_q2,
    const float* __restrict__ Wiht, const float* __restrict__ b_ih,
    float* __restrict__ h0, float* __restrict__ h1,
    float* __restrict__ CA, float* __restrict__ out)
{
    cg::grid_group grid = cg::this_grid();
    __shared__ union SMem {
        struct { float H[64][68]; float W[64][64]; } a;  // phase A staging
        struct { float Q[4][64]; float Z[4][32]; } b;    // phase B stats/z
    } sm;
    const int tid = threadIdx.x;

    for (int t = 0; t < TT; ++t) {
        const float* hcur = (t & 1) ? h1 : h0;
        float* hnext = (t & 1) ? h0 : h1;

        // ======== Phase A: CA[1024][1280] = f(hcur @ Wcombt) ========
        for (int tile = blockIdx.x; tile < 16 * 20; tile += gridDim.x) {
            const int rt = tile / 20, ct = tile - rt * 20;
            const int r0 = rt * 64, c0 = ct * 64;
            const int tx = tid & 15, ty = tid >> 4;
            const int cloc = tx * 4;
            float acc[4][4] = {{0.f}};
            for (int kc = 0; kc < 4; ++kc) {
                const int k0 = kc * 64;
                __syncthreads();
#pragma unroll
                for (int l = 0; l < 4; ++l) {
                    int idx = l * 1024 + tid * 4;
                    int i = idx >> 6, kk = idx & 63;
                    *(float4*)&sm.a.H[i][kk] = *(const float4*)&hcur[(r0 + i) * DD + k0 + kk];
                    *(float4*)&sm.a.W[i][kk] = *(const float4*)&Wcombt[(k0 + i) * NC + c0 + kk];
                }
                __syncthreads();
#pragma unroll 8
                for (int kk = 0; kk < 64; ++kk) {
                    float4 w = *(const float4*)&sm.a.W[kk][cloc];
                    float a0 = sm.a.H[ty * 4 + 0][kk];
                    float a1 = sm.a.H[ty * 4 + 1][kk];
                    float a2 = sm.a.H[ty * 4 + 2][kk];
                    float a3 = sm.a.H[ty * 4 + 3][kk];
                    acc[0][0] += a0 * w.x; acc[0][1] += a0 * w.y; acc[0][2] += a0 * w.z; acc[0][3] += a0 * w.w;
                    acc[1][0] += a1 * w.x; acc[1][1] += a1 * w.y; acc[1][2] += a1 * w.z; acc[1][3] += a1 * w.w;
                    acc[2][0] += a2 * w.x; acc[2][1] += a2 * w.y; acc[2][2] += a2 * w.z; acc[2][3] += a2 * w.w;
                    acc[3][0] += a3 * w.x; acc[3][1] += a3 * w.y; acc[3][2] += a3 * w.z; acc[3][3] += a3 * w.w;
                }
            }
            const int gcol = c0 + cloc;
#pragma unroll
            for (int i = 0; i < 4; ++i) {
                const int grow = r0 + ty * 4 + i;
                float* crow = CA + (size_t)grow * NC + gcol;
                if (c0 < 256) {            // P1 = elu(x + b_p1)
#pragma unroll
                    for (int j = 0; j < 4; ++j) crow[j] = eluf(acc[i][j] + b_p1[gcol + j]);
                } else if (c0 < 512) {     // Q1 = elu(x + Qpre[t])  (Qpre already has b_q1)
                    const QT* qp = Qpre + ((size_t)t * BB + grow) * HHID + (gcol - 256);
#pragma unroll
                    for (int j = 0; j < 4; ++j) crow[j] = eluf(acc[i][j] + (float)qp[j]);
                } else {                   // gh = x + b_hh
#pragma unroll
                    for (int j = 0; j < 4; ++j) crow[j] = acc[i][j] + b_hh[gcol - 512 + j];
                }
            }
        }
        grid.sync();

        // ======== Phase B: per-row stats, z, GRU, output ========
        {
            const int g = tid >> 6, lane = tid & 63;
            const int r = blockIdx.x * 4 + g;
            const float* car = CA + (size_t)r * NC;
            float* orow = out + (size_t)(r * TT + t) * 416;

            // prior stats (K=256 over P1)
            float d = b_p2[lane];
#pragma unroll 8
            for (int k = 0; k < 256; ++k) d += car[k] * Wp2t[k * 64 + lane];
            if (lane < 32) orow[288 + lane] = d;                     // prior mean
            else orow[320 + (lane - 32)] = expf(clip75(d));          // prior std

            // posterior stats (K=256 over Q1)
            float d2 = b_q2[lane];
#pragma unroll 8
            for (int k = 0; k < 256; ++k) d2 += car[256 + k] * Wq2t[k * 64 + lane];
            float sv;
            if (lane < 32) { sv = d2; orow[352 + lane] = d2; }       // post mean
            else { sv = expf(clip75(d2)); orow[384 + (lane - 32)] = sv; }  // post std
            sm.b.Q[g][lane] = sv;
            __syncthreads();

            if (lane < 32) {
                float z = sm.b.Q[g][lane] +
                          sm.b.Q[g][lane + 32] * noise[((size_t)t * BB + r) * SS + lane];
                sm.b.Z[g][lane] = z;
                orow[256 + lane] = z;
            }
            __syncthreads();

            // GRU gates; j = jj*64 + lane covers 0..255
            float a8[8];
            const float* arow = act + (size_t)(r * TT + t) * 8;
#pragma unroll
            for (int k = 0; k < 8; ++k) a8[k] = arow[k];
#pragma unroll
            for (int jj = 0; jj < 4; ++jj) {
                const int j = jj * 64 + lane;
                float gr = b_ih[j], gz = b_ih[256 + j], gn = b_ih[512 + j];
#pragma unroll 8
                for (int k = 0; k < 32; ++k) {
                    float zk = sm.b.Z[g][k];
                    gr += zk * Wiht[k * 768 + j];
                    gz += zk * Wiht[k * 768 + 256 + j];
                    gn += zk * Wiht[k * 768 + 512 + j];
                }
#pragma unroll
                for (int k = 0; k < 8; ++k) {
                    gr += a8[k] * Wiht[(32 + k) * 768 + j];
                    gz += a8[k] * Wiht[(32 + k) * 768 + 256 + j];
                    gn += a8[k] * Wiht[(32 + k) * 768 + 512 + j];
                }
                float rg = sigf(gr + car[512 + j]);
                float ug = sigf(gz + car[768 + j]);
                float ng = tanhf(gn + rg * car[1024 + j]);
                float hold = hcur[(size_t)r * DD + j];
                hnext[(size_t)r * DD + j] = (1.f - ug) * ng + ug * hold;
                orow[j] = hold;
            }
        }
        grid.sync();
    }
}

extern "C" void kernel_launch(void* const* d_in, const int* in_sizes, int n_in,
                              void* d_out, int out_size, void* d_ws, size_t ws_size,
                              hipStream_t stream)
{
    const float* obs   = (const float*)d_in[0];
    const float* act   = (const float*)d_in[1];
    const float* noise = (const float*)d_in[2];
    const float* W_e1  = (const float*)d_in[3];
    const float* b_e1  = (const float*)d_in[4];
    const float* W_e2  = (const float*)d_in[5];
    const float* b_e2  = (const float*)d_in[6];
    const float* W_ih  = (const float*)d_in[7];
    const float* W_hh  = (const float*)d_in[8];
    const float* b_ih  = (const float*)d_in[9];
    const float* b_hh  = (const float*)d_in[10];
    const float* W_p1  = (const float*)d_in[11];
    const float* b_p1  = (const float*)d_in[12];
    const float* W_p2  = (const float*)d_in[13];
    const float* b_p2  = (const float*)d_in[14];
    const float* W_q1  = (const float*)d_in[15];
    const float* b_q1  = (const float*)d_in[16];
    const float* W_q2  = (const float*)d_in[17];
    const float* b_q2  = (const float*)d_in[18];
    float* outp = (float*)d_out;

    // fixed float buffers after the Qpre region
    const size_t qpre_elems = (size_t)TT * BB * HHID;                 // 33,554,432
    const size_t fixed_floats =
        256 * 1280 + 64 * 256 + 256 * 256 + 256 * 256 + 256 * 64 + 256 * 64 +
        40 * 768 + 2 * (size_t)BB * DD + (size_t)BB * NC;
    const size_t fixed_bytes = fixed_floats * sizeof(float);

    bool use_f32 = ws_size >= fixed_bytes + qpre_elems * sizeof(float);
    bool use_bf16 = !use_f32 && ws_size >= fixed_bytes + qpre_elems * sizeof(__hip_bfloat16);
    if (!use_f32 && !use_bf16) return;  // workspace too small; nothing safe to do

    char* wsb = (char*)d_ws;
    void* QpreV = (void*)wsb;
    size_t qpre_bytes = qpre_elems * (use_f32 ? sizeof(float) : sizeof(__hip_bfloat16));
    float* f = (float*)(wsb + qpre_bytes);
    float* Wcombt = f;            f += 256 * 1280;
    float* We1t   = f;            f += 64 * 256;
    float* We2t   = f;            f += 256 * 256;
    float* Wq1et  = f;            f += 256 * 256;
    float* Wp2t   = f;            f += 256 * 64;
    float* Wq2t   = f;            f += 256 * 64;
    float* Wiht   = f;            f += 40 * 768;
    float* h0     = f;            f += (size_t)BB * DD;
    float* h1     = f;            f += (size_t)BB * DD;
    float* CA     = f;            f += (size_t)BB * NC;

    auto tl = [&](const float* s, float* d, int N, int K, int soff, int sld, int dld, int dcoff) {
        int tot = N * K;
        transpose_k<<<(tot + 255) / 256, 256, 0, stream>>>(s, d, N, K, soff, sld, dld, dcoff);
    };
    tl(W_p1, Wcombt, 256, 256, 0, 256, 1280, 0);     // P1 weights -> cols 0..255
    tl(W_q1, Wcombt, 256, 256, 0, 512, 1280, 256);   // Wq1 h-part -> cols 256..511
    tl(W_hh, Wcombt, 768, 256, 0, 256, 1280, 512);   // gh weights -> cols 512..1279
    tl(W_e1, We1t, 256, 64, 0, 64, 256, 0);
    tl(W_e2, We2t, 256, 256, 0, 256, 256, 0);
    tl(W_q1, Wq1et, 256, 256, 256, 512, 256, 0);     // Wq1 emb-part
    tl(W_p2, Wp2t, 64, 256, 0, 256, 64, 0);
    tl(W_q2, Wq2t, 64, 256, 0, 256, 64, 0);
    tl(W_ih, Wiht, 768, 40, 0, 40, 768, 0);

    hipMemsetAsync(h0, 0, (size_t)BB * DD * sizeof(float), stream);

    if (use_f32) {
        float* Qpre = (float*)QpreV;
        obs_enc_k<float><<<dim3((BB * TT) / 32), dim3(256), 0, stream>>>(
            obs, We1t, b_e1, We2t, b_e2, Wq1et, b_q1, Qpre);
        const float* Qp = Qpre;
        void* args[] = { (void*)&act, (void*)&noise, (void*)&Wcombt, (void*)&b_p1, (void*)&b_hh,
                         (void*)&Qp, (void*)&Wp2t, (void*)&b_p2, (void*)&Wq2t, (void*)&b_q2,
                         (void*)&Wiht, (void*)&b_ih, (void*)&h0, (void*)&h1, (void*)&CA, (void*)&outp };
        hipLaunchCooperativeKernel((void*)seq_k<float>, dim3(256), dim3(256), args, 0, stream);
    } else {
        __hip_bfloat16* Qpre = (__hip_bfloat16*)QpreV;
        obs_enc_k<__hip_bfloat16><<<dim3((BB * TT) / 32), dim3(256), 0, stream>>>(
            obs, We1t, b_e1, We2t, b_e2, Wq1et, b_q1, Qpre);
        const __hip_bfloat16* Qp = Qpre;
        void* args[] = { (void*)&act, (void*)&noise, (void*)&Wcombt, (void*)&b_p1, (void*)&b_hh,
                         (void*)&Qp, (void*)&Wp2t, (void*)&b_p2, (void*)&Wq2t, (void*)&b_q2,
                         (void*)&Wiht, (void*)&b_ih, (void*)&h0, (void*)&h1, (void*)&CA, (void*)&outp };
        hipLaunchCooperativeKernel((void*)seq_k<__hip_bfloat16>, dim3(256), dim3(256), args, 0, stream);
    }
}

// Round 2
// 3222.604 us; speedup vs baseline: 4.7996x; 4.7996x over previous
//
#include <hip/hip_runtime.h>
#include <hip/hip_bf16.h>
#include <string.h>

#define TT 128   // time steps
#define BB 1024  // batch
#define DD 256   // deter dim
#define SS 32    // stoch dim
#define HHID 256 // hidden
#define NC 1280  // combined phase-A cols: 256 P1 | 256 Q1 | 768 gh

typedef __attribute__((ext_vector_type(8))) short bf16x8;
typedef __attribute__((ext_vector_type(4))) float f32x4;

__device__ __forceinline__ float eluf(float x)   { return x > 0.f ? x : __expf(x) - 1.f; }
__device__ __forceinline__ float sigf(float x)   { return 1.f / (1.f + __expf(-x)); }
__device__ __forceinline__ float tanhf_(float x) { float e = __expf(2.f * x); return (e - 1.f) / (e + 1.f); }
__device__ __forceinline__ float clip75(float x) { return fminf(fmaxf(x, -7.f), 5.f); }

// unpack a uint holding two bf16 (low ushort = first element) to float2
__device__ __forceinline__ float2 bf2f2(unsigned int u) {
    union { unsigned int i; float f; } a, b;
    a.i = (u & 0xffffu) << 16;
    b.i = u & 0xffff0000u;
    return make_float2(a.f, b.f);
}

// ---------------- weight transpose (for obs encoder): dst[k*dld + dcoff + n] = src[n*sld + soff + k] ----
__global__ void transpose_k(const float* __restrict__ src, float* __restrict__ dst,
                            int N, int K, int soff, int sld, int dld, int dcoff)
{
    int idx = blockIdx.x * 256 + threadIdx.x;
    if (idx >= N * K) return;
    int k = idx / N, n = idx - k * N;
    dst[k * dld + dcoff + n] = src[n * sld + soff + k];
}

// ---------------- prep: Wcomb -> MFMA B-fragment-major bf16 ----------------
// dst[((nt*8+ks)*64+lane)*8 + j] = Wcomb[nt*16 + (lane&15)][ks*32 + (lane>>4)*8 + j]
// Wcomb rows: [0,256)=W_p1, [256,512)=W_q1 h-part, [512,1280)=W_hh
__global__ void prep_wcomb(const float* __restrict__ Wp1, const float* __restrict__ Wq1,
                           const float* __restrict__ Whh, __hip_bfloat16* __restrict__ dst)
{
    int idx = blockIdx.x * 256 + threadIdx.x;
    if (idx >= NC * DD) return;
    int j = idx & 7, lane = (idx >> 3) & 63, ks = (idx >> 9) & 7, nt = idx >> 12;
    int n = nt * 16 + (lane & 15);
    int k = ks * 32 + (lane >> 4) * 8 + j;
    float v;
    if (n < 256)      v = Wp1[n * 256 + k];
    else if (n < 512) v = Wq1[(n - 256) * 512 + k];
    else              v = Whh[(n - 512) * 256 + k];
    dst[idx] = __float2bfloat16(v);
}

// ---------------- prep: W2 [64][256] -> paired-k bf16: dst[(kp*64+l)*2+par] = W[l][kp*2+par] ----
__global__ void prep_w2(const float* __restrict__ W, __hip_bfloat16* __restrict__ dst)
{
    int idx = blockIdx.x * 256 + threadIdx.x;
    if (idx >= 64 * 256) return;
    int par = idx & 1, l = (idx >> 1) & 63, kp = idx >> 7;
    dst[idx] = __float2bfloat16(W[l * 256 + kp * 2 + par]);
}

// ---------------- prep: W_ih [768][40] -> [kp][gate][j][par] bf16 ----------------
// dst[((kp*3+g)*256 + j)*2 + par] = W_ih[(g*256+j)*40 + kp*2+par]
__global__ void prep_wih(const float* __restrict__ W, __hip_bfloat16* __restrict__ dst)
{
    int idx = blockIdx.x * 256 + threadIdx.x;
    if (idx >= 768 * 40) return;
    int par = idx & 1;
    int t = idx >> 1;
    int j = t & 255;
    int t2 = t >> 8;          // kp*3 + g, 0..59
    int g = t2 % 3, kp = t2 / 3;
    dst[idx] = __float2bfloat16(W[(g * 256 + j) * 40 + kp * 2 + par]);
}

// ---------------- fused obs encoder -> Qpre[t][b][:] = emb @ Wq1_e^T + b_q1 (fp32) ----------------
__global__ void __launch_bounds__(256) obs_enc_k(
    const float* __restrict__ obs, const float* __restrict__ We1t,
    const float* __restrict__ be1, const float* __restrict__ We2t,
    const float* __restrict__ be2, const float* __restrict__ Wq1et,
    const float* __restrict__ bq1, float* __restrict__ Qpre)
{
    __shared__ float buf0[32 * 256];
    __shared__ float buf1[32 * 256];
    const int tid = threadIdx.x;
    const int r0 = blockIdx.x * 32;
    const int tx = tid & 31, ty = tid >> 5;
    const int colb = tx * 8;
    float acc[4][8];

#pragma unroll
    for (int i = 0; i < 4; ++i)
#pragma unroll
        for (int j = 0; j < 8; ++j) acc[i][j] = 0.f;
#pragma unroll 4
    for (int k = 0; k < 64; ++k) {
        float4 w0 = *(const float4*)&We1t[k * 256 + colb];
        float4 w1 = *(const float4*)&We1t[k * 256 + colb + 4];
#pragma unroll
        for (int i = 0; i < 4; ++i) {
            float a = obs[(r0 + ty * 4 + i) * 64 + k];
            acc[i][0] += a * w0.x; acc[i][1] += a * w0.y; acc[i][2] += a * w0.z; acc[i][3] += a * w0.w;
            acc[i][4] += a * w1.x; acc[i][5] += a * w1.y; acc[i][6] += a * w1.z; acc[i][7] += a * w1.w;
        }
    }
#pragma unroll
    for (int i = 0; i < 4; ++i)
#pragma unroll
        for (int j = 0; j < 8; ++j)
            buf0[(ty * 4 + i) * 256 + colb + j] = eluf(acc[i][j] + be1[colb + j]);
    __syncthreads();

#pragma unroll
    for (int i = 0; i < 4; ++i)
#pragma unroll
        for (int j = 0; j < 8; ++j) acc[i][j] = 0.f;
#pragma unroll 4
    for (int k = 0; k < 256; ++k) {
        float4 w0 = *(const float4*)&We2t[k * 256 + colb];
        float4 w1 = *(const float4*)&We2t[k * 256 + colb + 4];
#pragma unroll
        for (int i = 0; i < 4; ++i) {
            float a = buf0[(ty * 4 + i) * 256 + k];
            acc[i][0] += a * w0.x; acc[i][1] += a * w0.y; acc[i][2] += a * w0.z; acc[i][3] += a * w0.w;
            acc[i][4] += a * w1.x; acc[i][5] += a * w1.y; acc[i][6] += a * w1.z; acc[i][7] += a * w1.w;
        }
    }
#pragma unroll
    for (int i = 0; i < 4; ++i)
#pragma unroll
        for (int j = 0; j < 8; ++j)
            buf1[(ty * 4 + i) * 256 + colb + j] = eluf(acc[i][j] + be2[colb + j]);
    __syncthreads();

#pragma unroll
    for (int i = 0; i < 4; ++i)
#pragma unroll
        for (int j = 0; j < 8; ++j) acc[i][j] = 0.f;
#pragma unroll 4
    for (int k = 0; k < 256; ++k) {
        float4 w0 = *(const float4*)&Wq1et[k * 256 + colb];
        float4 w1 = *(const float4*)&Wq1et[k * 256 + colb + 4];
#pragma unroll
        for (int i = 0; i < 4; ++i) {
            float a = buf1[(ty * 4 + i) * 256 + k];
            acc[i][0] += a * w0.x; acc[i][1] += a * w0.y; acc[i][2] += a * w0.z; acc[i][3] += a * w0.w;
            acc[i][4] += a * w1.x; acc[i][5] += a * w1.y; acc[i][6] += a * w1.z; acc[i][7] += a * w1.w;
        }
    }
#pragma unroll
    for (int i = 0; i < 4; ++i) {
        int r = r0 + ty * 4 + i;
        int b = r >> 7, t = r & (TT - 1);   // row = b*T + t
        float* dst = Qpre + ((size_t)t * BB + b) * HHID + colb;
#pragma unroll
        for (int j = 0; j < 8; ++j)
            dst[j] = acc[i][j] + bq1[colb + j];
    }
}

// ---------------- main sequential kernel: block = 4 batch rows, loops all T internally ----------------
__global__ void __launch_bounds__(256, 1) rssm_seq(
    const float* __restrict__ act, const float* __restrict__ noise,
    const __hip_bfloat16* __restrict__ Wfrag, const float* __restrict__ b_p1,
    const float* __restrict__ b_hh, const float* __restrict__ Qpre,
    const unsigned int* __restrict__ Wp2p, const float* __restrict__ b_p2,
    const unsigned int* __restrict__ Wq2p, const float* __restrict__ b_q2,
    const unsigned int* __restrict__ Wihp, const float* __restrict__ b_ih,
    float* __restrict__ out)
{
    __shared__ float CA[4][NC];                 // P1 | Q1 | gh for our 4 rows
    __shared__ float h32[4][DD];
    __shared__ __hip_bfloat16 hbf[16][264];     // MFMA A operand, rows 4..15 zero, +8 pad
    __shared__ float zl[4][SS];
    __shared__ float actl[4][8];

    const int tid = threadIdx.x;
    const int wave = tid >> 6, lane = tid & 63;
    const int blk = blockIdx.x;

    for (int i = tid; i < 16 * 264; i += 256) ((unsigned short*)hbf)[i] = 0;
    for (int i = tid; i < 4 * DD; i += 256) ((float*)h32)[i] = 0.f;
    __syncthreads();

    const int am = lane & 15, aq = lane >> 4;
    // wave handles N-tiles nt = wave*20 + i; short8 frag index = (nt*8+ks)*64 + lane
    const bf16x8* wp = (const bf16x8*)Wfrag + (size_t)wave * 160 * 64 + lane;

    for (int t = 0; t < TT; ++t) {
        if (tid < 32) {
            int row = tid >> 3, c = tid & 7;
            actl[row][c] = act[((size_t)(blk * 4 + row) * TT + t) * 8 + c];
        }

        // ======== Phase A: CA[4][1280] = epilogue(h @ Wcomb^T) via MFMA ========
        bf16x8 afr[8];
#pragma unroll
        for (int ks = 0; ks < 8; ++ks)
            afr[ks] = *(const bf16x8*)&hbf[am][ks * 32 + aq * 8];

        bf16x8 bbuf[2][8];
#pragma unroll
        for (int ks = 0; ks < 8; ++ks) bbuf[0][ks] = wp[(size_t)ks * 64];
#pragma unroll 2
        for (int i = 0; i < 20; ++i) {
            const int cb = i & 1;
            if (i < 19) {
#pragma unroll
                for (int ks = 0; ks < 8; ++ks)
                    bbuf[cb ^ 1][ks] = wp[(size_t)((i + 1) * 8 + ks) * 64];
            }
            f32x4 acc = {0.f, 0.f, 0.f, 0.f};
#pragma unroll
            for (int ks = 0; ks < 8; ++ks)
                acc = __builtin_amdgcn_mfma_f32_16x16x32_bf16(afr[ks], bbuf[cb][ks], acc, 0, 0, 0);
            const int nt = wave * 20 + i;
            if (lane < 16) {   // quad 0 holds rows 0..3 (row = reg, col = nt*16+lane)
                const int col = nt * 16 + lane;
                if (nt < 16) {
#pragma unroll
                    for (int reg = 0; reg < 4; ++reg)
                        CA[reg][col] = eluf(acc[reg] + b_p1[col]);
                } else if (nt < 32) {
#pragma unroll
                    for (int reg = 0; reg < 4; ++reg)
                        CA[reg][col] = eluf(acc[reg] +
                            Qpre[((size_t)t * BB + blk * 4 + reg) * HHID + (col - 256)]);
                } else {
#pragma unroll
                    for (int reg = 0; reg < 4; ++reg)
                        CA[reg][col] = acc[reg] + b_hh[col - 512];
                }
            }
        }
        __syncthreads();

        // ======== Phase B1: stats (wave = row), z ========
        {
            const float* car = CA[wave];
            float dp = b_p2[lane], dq = b_q2[lane];
#pragma unroll 4
            for (int kp = 0; kp < 128; ++kp) {
                float2 ap = *(const float2*)&car[kp * 2];
                float2 wr = bf2f2(Wp2p[kp * 64 + lane]);
                dp += ap.x * wr.x + ap.y * wr.y;
                float2 aq2 = *(const float2*)&car[256 + kp * 2];
                float2 wq = bf2f2(Wq2p[kp * 64 + lane]);
                dq += aq2.x * wq.x + aq2.y * wq.y;
            }
            const int r = blk * 4 + wave;
            float* orow = out + ((size_t)r * TT + t) * 416;
            float pv = (lane < 32) ? dp : __expf(clip75(dp));
            orow[288 + lane] = pv;                       // prior mean | prior std
            float qv = (lane < 32) ? dq : __expf(clip75(dq));
            orow[352 + lane] = qv;                       // post mean | post std
            float qs_hi = __shfl(qv, lane + 32, 64);
            if (lane < 32) {
                float z = qv + qs_hi * noise[((size_t)t * BB + r) * SS + lane];
                zl[wave][lane] = z;
                orow[256 + lane] = z;
            }
        }
        __syncthreads();

        // ======== Phase B2: GRU (thread = column j, all 4 rows) ========
        {
            const int j = tid;
            float g0[4], g1[4], g2[4];
            float br = b_ih[j], bz = b_ih[256 + j], bn = b_ih[512 + j];
#pragma unroll
            for (int r4 = 0; r4 < 4; ++r4) { g0[r4] = br; g1[r4] = bz; g2[r4] = bn; }
#pragma unroll 4
            for (int kp = 0; kp < 16; ++kp) {            // z part: k = 0..31
                float2 wr = bf2f2(Wihp[(kp * 3 + 0) * 256 + j]);
                float2 wz = bf2f2(Wihp[(kp * 3 + 1) * 256 + j]);
                float2 wn = bf2f2(Wihp[(kp * 3 + 2) * 256 + j]);
#pragma unroll
                for (int r4 = 0; r4 < 4; ++r4) {
                    float2 zz = *(const float2*)&zl[r4][kp * 2];
                    g0[r4] += zz.x * wr.x + zz.y * wr.y;
                    g1[r4] += zz.x * wz.x + zz.y * wz.y;
                    g2[r4] += zz.x * wn.x + zz.y * wn.y;
                }
            }
#pragma unroll
            for (int kp = 16; kp < 20; ++kp) {           // act part: k = 32..39
                float2 wr = bf2f2(Wihp[(kp * 3 + 0) * 256 + j]);
                float2 wz = bf2f2(Wihp[(kp * 3 + 1) * 256 + j]);
                float2 wn = bf2f2(Wihp[(kp * 3 + 2) * 256 + j]);
#pragma unroll
                for (int r4 = 0; r4 < 4; ++r4) {
                    float2 aa = *(const float2*)&actl[r4][(kp - 16) * 2];
                    g0[r4] += aa.x * wr.x + aa.y * wr.y;
                    g1[r4] += aa.x * wz.x + aa.y * wz.y;
                    g2[r4] += aa.x * wn.x + aa.y * wn.y;
                }
            }
#pragma unroll
            for (int r4 = 0; r4 < 4; ++r4) {
                float rg = sigf(g0[r4] + CA[r4][512 + j]);
                float ug = sigf(g1[r4] + CA[r4][768 + j]);
                float ng = tanhf_(g2[r4] + rg * CA[r4][1024 + j]);
                float hold = h32[r4][j];
                float hn = (1.f - ug) * ng + ug * hold;
                out[((size_t)(blk * 4 + r4) * TT + t) * 416 + j] = hold;  // h at step entry
                h32[r4][j] = hn;
                hbf[r4][j] = __float2bfloat16(hn);
            }
        }
        __syncthreads();   // hbf/h32/CA stable before next step's Phase A
    }
}

extern "C" void kernel_launch(void* const* d_in, const int* in_sizes, int n_in,
                              void* d_out, int out_size, void* d_ws, size_t ws_size,
                              hipStream_t stream)
{
    const float* obs   = (const float*)d_in[0];
    const float* act   = (const float*)d_in[1];
    const float* noise = (const float*)d_in[2];
    const float* W_e1  = (const float*)d_in[3];
    const float* b_e1  = (const float*)d_in[4];
    const float* W_e2  = (const float*)d_in[5];
    const float* b_e2  = (const float*)d_in[6];
    const float* W_ih  = (const float*)d_in[7];
    const float* W_hh  = (const float*)d_in[8];
    const float* b_ih  = (const float*)d_in[9];
    const float* b_hh  = (const float*)d_in[10];
    const float* W_p1  = (const float*)d_in[11];
    const float* b_p1  = (const float*)d_in[12];
    const float* W_p2  = (const float*)d_in[13];
    const float* b_p2  = (const float*)d_in[14];
    const float* W_q1  = (const float*)d_in[15];
    const float* b_q1  = (const float*)d_in[16];
    const float* W_q2  = (const float*)d_in[17];
    const float* b_q2  = (const float*)d_in[18];
    float* outp = (float*)d_out;

    // workspace layout
    const size_t qpre_elems = (size_t)TT * BB * HHID;           // 33,554,432 f32
    float* Qpre  = (float*)d_ws;
    float* We1t  = Qpre + qpre_elems;       // 64*256
    float* We2t  = We1t + 64 * 256;         // 256*256
    float* Wq1et = We2t + 256 * 256;        // 256*256
    __hip_bfloat16* Wfrag = (__hip_bfloat16*)(Wq1et + 256 * 256);  // 1280*256
    __hip_bfloat16* Wp2b  = Wfrag + NC * DD;                       // 16384
    __hip_bfloat16* Wq2b  = Wp2b + 64 * 256;                       // 16384
    __hip_bfloat16* Wihb  = Wq2b + 64 * 256;                       // 30720
    size_t total_bytes = (char*)(Wihb + 768 * 40) - (char*)d_ws;
    if (ws_size < total_bytes) return;

    auto tl = [&](const float* s, float* d, int N, int K, int soff, int sld, int dld, int dcoff) {
        int tot = N * K;
        transpose_k<<<(tot + 255) / 256, 256, 0, stream>>>(s, d, N, K, soff, sld, dld, dcoff);
    };
    tl(W_e1, We1t, 256, 64, 0, 64, 256, 0);
    tl(W_e2, We2t, 256, 256, 0, 256, 256, 0);
    tl(W_q1, Wq1et, 256, 256, 256, 512, 256, 0);   // emb-part of W_q1

    prep_wcomb<<<(NC * DD + 255) / 256, 256, 0, stream>>>(W_p1, W_q1, W_hh, Wfrag);
    prep_w2<<<(64 * 256 + 255) / 256, 256, 0, stream>>>(W_p2, Wp2b);
    prep_w2<<<(64 * 256 + 255) / 256, 256, 0, stream>>>(W_q2, Wq2b);
    prep_wih<<<(768 * 40 + 255) / 256, 256, 0, stream>>>(W_ih, Wihb);

    obs_enc_k<<<dim3((BB * TT) / 32), dim3(256), 0, stream>>>(
        obs, We1t, b_e1, We2t, b_e2, Wq1et, b_q1, Qpre);

    rssm_seq<<<dim3(BB / 4), dim3(256), 0, stream>>>(
        act, noise, Wfrag, b_p1, b_hh, Qpre,
        (const unsigned int*)Wp2b, b_p2,
        (const unsigned int*)Wq2b, b_q2,
        (const unsigned int*)Wihb, b_ih, outp);
}